// Round 13
// baseline (436.843 us; speedup 1.0000x reference)
//
#include <hip/hip_runtime.h>
#include <hip/hip_bf16.h>

#define B_ 32
#define C_ 48
#define H_ 64
#define W_ 128
#define K_ 5
#define SLAB (C_*H_*W_)
#define RS 56                 // carry row stride in bf16 shorts (112 B)
#define ROWS 136              // rows 0..133 data+halo, row 135 = const-1 block
#define CBUF (ROWS*RS)
#define WC (W_*C_)
#define HC (H_*C_)
#define KBN 16                // K' = 256: 15 real kb (K'=240) + 1 bias/pad kb
#define C1ROW 135

typedef __attribute__((ext_vector_type(8))) short short8;
typedef __attribute__((ext_vector_type(16))) float f32x16;
typedef unsigned short ushort;

__device__ __forceinline__ void lbar() {
  asm volatile("s_waitcnt lgkmcnt(0)\n\ts_barrier" ::: "memory");
}

__device__ __forceinline__ unsigned short f2bf(float f) {
  union { float f; unsigned u; } v; v.f = f;
  unsigned r = v.u + 0x7fffu + ((v.u >> 16) & 1u);
  return (unsigned short)(r >> 16);
}

__device__ __forceinline__ unsigned pk2(float a, float b) {
  union { __hip_bfloat162 h; unsigned u; } z;
  z.h = __float22bfloat162_rn(float2{a, b});
  return z.u;
}

// Weights as 32x32x16 MFMA A operand. Lane l: m = mt*32 + (l&31),
// k' = kbn*16 + (l>>5)*8 + j. kp<240: dense k'=k*48+i; kp==240: bias[m]
// (pairs with const-1.0 B slot); else 0. m>=48 pad -> 0.
template<int NMT>
__device__ __forceinline__ void load_wA32(const float* __restrict__ wgt,
                                          const float* __restrict__ bias,
                                          short8 Aw[NMT][KBN], int mt0,
                                          int l31, int h) {
#pragma unroll
  for (int mti = 0; mti < NMT; ++mti) {
    const int m = (mt0 + mti) * 32 + l31;
#pragma unroll
    for (int kbn = 0; kbn < KBN; ++kbn) {
      short8 f;
#pragma unroll
      for (int j = 0; j < 8; ++j) {
        int kp = kbn * 16 + h * 8 + j;
        float val = 0.f;
        if (m < C_) {
          if (kp < 240) {
            int k = kp / 48, i = kp - 48 * k;
            val = wgt[m * (C_ * K_) + i * K_ + k];
          } else if (kp == 240) {
            val = bias[m];
          }
        }
        f[j] = (short)f2bf(val);
      }
      Aw[mti][kbn] = f;
    }
  }
}

// Load 6 channel-group float4s (W layout: mt0 g0-3, mt1 g0-1)
__device__ __forceinline__ void loadx6(float4 xv[6], const float* __restrict__ inp,
                                       size_t inRS, int n0, int l31, int h4) {
  const float* ip = inp + (size_t)(n0 + l31) * inRS + h4;
  xv[0] = *(const float4*)(ip + 0);
  xv[1] = *(const float4*)(ip + 8);
  xv[2] = *(const float4*)(ip + 16);
  xv[3] = *(const float4*)(ip + 24);
  xv[4] = *(const float4*)(ip + 32);
  xv[5] = *(const float4*)(ip + 40);
}

// ---- W step: 1 Ntile (32 rows) x 2 Mtiles, 32 MFMA. Prefetches next xin
// AFTER the MFMA block (consumed next step -> full-step latency coverage).
__device__ __forceinline__ void stepW32(const ushort* __restrict__ scr,
                                        ushort* __restrict__ scw,
                                        const short8 Aw[2][KBN],
                                        const float4 xvc[6], float4 xvn[6],
                                        const float* __restrict__ inpn, size_t inRS,
                                        float* __restrict__ outp,
                                        int n0, int l31, int h4,
                                        const int off_r[KBN], int c1off) {
  f32x16 a0 = (f32x16)(0.0f), a1 = (f32x16)(0.0f);
  const ushort* bp = scr + (size_t)n0 * RS;
#pragma unroll
  for (int kbn = 0; kbn < KBN; ++kbn) {
    int off = (kbn == 15) ? c1off : off_r[kbn];
    short8 pf = *(const short8*)(bp + off);
    a0 = __builtin_amdgcn_mfma_f32_32x32x16_bf16(Aw[0][kbn], pf, a0, 0, 0, 0);
    a1 = __builtin_amdgcn_mfma_f32_32x32x16_bf16(Aw[1][kbn], pf, a1, 0, 0, 0);
  }
  loadx6(xvn, inpn, inRS, n0, l31, h4);   // next-step inputs
  __builtin_amdgcn_sched_barrier(0);

  const int row = n0 + l31;
  float* op = outp + (size_t)row * C_ + h4;
  ushort* wp = scw + (size_t)(row + 2) * RS + h4;
#pragma unroll
  for (int grp = 0; grp < 6; ++grp) {
    const int g = (grp < 4) ? grp : (grp - 4);
    const int ch = ((grp < 4) ? 0 : 32) + 8 * g;
    f32x16 A = (grp < 4) ? a0 : a1;
    float4 v;
    v.x = A[4*g+0] + xvc[grp].x; v.y = A[4*g+1] + xvc[grp].y;
    v.z = A[4*g+2] + xvc[grp].z; v.w = A[4*g+3] + xvc[grp].w;
    *(float4*)(op + ch) = v;
    uint2 pk; pk.x = pk2(v.x, v.y); pk.y = pk2(v.z, v.w);
    *(uint2*)(wp + ch) = pk;
  }
  lbar();
}

// ---- H step: wave = (nt, mt); 16 MFMA, 2 accumulator chains.
template<int MT>
__device__ __forceinline__ void stepH32(const ushort* __restrict__ scr,
                                        ushort* __restrict__ scw,
                                        const short8 Aw[KBN],
                                        const float4 xvc[4], float4 xvn[4],
                                        const float* __restrict__ inpn, size_t inRS,
                                        float* __restrict__ outp,
                                        int n0, int l31, int h4,
                                        const int off_r[KBN], int c1off) {
  constexpr int NG = MT ? 2 : 4;
  f32x16 a0 = (f32x16)(0.0f), a1 = (f32x16)(0.0f);
  const ushort* bp = scr + (size_t)n0 * RS;
#pragma unroll
  for (int kbn = 0; kbn < KBN; ++kbn) {
    int off = (kbn == 15) ? c1off : off_r[kbn];
    short8 pf = *(const short8*)(bp + off);
    if (kbn & 1) a1 = __builtin_amdgcn_mfma_f32_32x32x16_bf16(Aw[kbn], pf, a1, 0, 0, 0);
    else         a0 = __builtin_amdgcn_mfma_f32_32x32x16_bf16(Aw[kbn], pf, a0, 0, 0, 0);
  }
  const int row = n0 + l31;
  {
    const float* ip = inpn + (size_t)row * inRS + MT * 32 + h4;
#pragma unroll
    for (int g = 0; g < NG; ++g) xvn[g] = *(const float4*)(ip + 8 * g);
  }
  __builtin_amdgcn_sched_barrier(0);

  float* op = outp + (size_t)row * C_ + MT * 32 + h4;
  ushort* wp = scw + (size_t)(row + 2) * RS + MT * 32 + h4;
#pragma unroll
  for (int g = 0; g < NG; ++g) {
    float4 v;
    v.x = a0[4*g+0] + a1[4*g+0] + xvc[g].x;
    v.y = a0[4*g+1] + a1[4*g+1] + xvc[g].y;
    v.z = a0[4*g+2] + a1[4*g+2] + xvc[g].z;
    v.w = a0[4*g+3] + a1[4*g+3] + xvc[g].w;
    *(float4*)(op + 8 * g) = v;
    uint2 pk; pk.x = pk2(v.x, v.y); pk.y = pk2(v.z, v.w);
    *(uint2*)(wp + 8 * g) = pk;
  }
  lbar();
}

// Pass-initial: carry = inp, out = inp (W layout: 6 groups).
__device__ __forceinline__ void initW(ushort* __restrict__ scw,
                                      const float* __restrict__ inp, size_t inRS,
                                      float* __restrict__ outp,
                                      int n0, int l31, int h4) {
  const int row = n0 + l31;
  const float* ip = inp + (size_t)row * inRS + h4;
  float* op = outp + (size_t)row * C_ + h4;
  ushort* wp = scw + (size_t)(row + 2) * RS + h4;
#pragma unroll
  for (int grp = 0; grp < 6; ++grp) {
    const int g = (grp < 4) ? grp : (grp - 4);
    const int ch = ((grp < 4) ? 0 : 32) + 8 * g;
    float4 v = *(const float4*)(ip + ch);
    *(float4*)(op + ch) = v;
    uint2 pk; pk.x = pk2(v.x, v.y); pk.y = pk2(v.z, v.w);
    *(uint2*)(wp + ch) = pk;
  }
  lbar();
}

template<int MT>
__device__ __forceinline__ void initH(ushort* __restrict__ scw,
                                      const float* __restrict__ inp, size_t inRS,
                                      float* __restrict__ outp,
                                      int n0, int l31, int h4) {
  constexpr int NG = MT ? 2 : 4;
  const int row = n0 + l31;
  const float* ip = inp + (size_t)row * inRS + MT * 32 + h4;
  float* op = outp + (size_t)row * C_ + MT * 32 + h4;
  ushort* wp = scw + (size_t)(row + 2) * RS + MT * 32 + h4;
#pragma unroll
  for (int g = 0; g < NG; ++g) {
    float4 v = *(const float4*)(ip + 8 * g);
    *(float4*)(op + 8 * g) = v;
    uint2 pk; pk.x = pk2(v.x, v.y); pk.y = pk2(v.z, v.w);
    *(uint2*)(wp + 8 * g) = pk;
  }
  lbar();
}

template<class FIN, class FOUT>
__device__ __forceinline__ void run_passW(ushort* sb, int& p,
                                          const short8 Aw[2][KBN],
                                          const int off_r[KBN], int c1off,
                                          int nsteps, FIN inadr, size_t inRS, FOUT outadr,
                                          int n0, int l31, int h4) {
  float4 xa[6], xb[6];
  loadx6(xa, inadr(1), inRS, n0, l31, h4);
  for (int s = 1; s <= nsteps; s += 2) {
    {
      int sn = (s + 1 <= nsteps) ? s + 1 : nsteps;
      stepW32(sb + (size_t)p * CBUF, sb + (size_t)(p ^ 1) * CBUF, Aw, xa, xb,
              inadr(sn), inRS, outadr(s), n0, l31, h4, off_r, c1off);
      p ^= 1;
    }
    if (s + 1 <= nsteps) {
      int sn = (s + 2 <= nsteps) ? s + 2 : nsteps;
      stepW32(sb + (size_t)p * CBUF, sb + (size_t)(p ^ 1) * CBUF, Aw, xb, xa,
              inadr(sn), inRS, outadr(s + 1), n0, l31, h4, off_r, c1off);
      p ^= 1;
    }
  }
}

template<int MT, class FIN, class FOUT>
__device__ __forceinline__ void run_passH(ushort* sb, int& p,
                                          const short8 Aw[KBN],
                                          const int off_r[KBN], int c1off,
                                          int nsteps, FIN inadr, size_t inRS, FOUT outadr,
                                          int n0, int l31, int h4) {
  float4 xa[4], xb[4];
  {
    const float* ip = inadr(1) + (size_t)(n0 + l31) * inRS + MT * 32 + h4;
#pragma unroll
    for (int g = 0; g < (MT ? 2 : 4); ++g) xa[g] = *(const float4*)(ip + 8 * g);
  }
  for (int s = 1; s <= nsteps; s += 2) {
    {
      int sn = (s + 1 <= nsteps) ? s + 1 : nsteps;
      stepH32<MT>(sb + (size_t)p * CBUF, sb + (size_t)(p ^ 1) * CBUF, Aw, xa, xb,
                  inadr(sn), inRS, outadr(s), n0, l31, h4, off_r, c1off);
      p ^= 1;
    }
    if (s + 1 <= nsteps) {
      int sn = (s + 2 <= nsteps) ? s + 2 : nsteps;
      stepH32<MT>(sb + (size_t)p * CBUF, sb + (size_t)(p ^ 1) * CBUF, Aw, xb, xa,
                  inadr(sn), inRS, outadr(s + 1), n0, l31, h4, off_r, c1off);
      p ^= 1;
    }
  }
}

__device__ __forceinline__ void zero_carry_c1(ushort* sb, int tid) {
  unsigned* z = (unsigned*)sb;
  for (int i = tid; i < CBUF; i += 256) z[i] = 0u;   // zeroes both buffers
  __syncthreads();
  if (tid == 0) { sb[C1ROW * RS] = 0x3F80; sb[CBUF + C1ROW * RS] = 0x3F80; }
}

// 4 waves (256 thr) per batch, grid 32. 32x32x16 MFMA.
// W passes: wave = Ntile wid (32 rows) x full M. H: wave = (nt=wid&1, mt=wid>>1).
__global__ __launch_bounds__(256, 1) void scnn_mfma(
    float* ws,                       // xT [b][h][w][c]; then R/L [b][t][h][c] (alias)
    const float* __restrict__ dw, const float* __restrict__ db,
    const float* __restrict__ rw, const float* __restrict__ rb,
    const float* __restrict__ lw, const float* __restrict__ lb,
    float* __restrict__ DU)          // d_out: D/U slabs [b][h][w][c]
{
  __shared__ __align__(32) ushort sb[2 * CBUF];
  const int tid = threadIdx.x, lane = tid & 63, wid = tid >> 6;
  const int l31 = lane & 31, h = lane >> 5, h4 = h * 4;
  const int b = blockIdx.x;
  float* xbuf = ws + (size_t)b * SLAB;
  float* rl   = ws + (size_t)b * SLAB;
  float* du   = DU + (size_t)b * SLAB;

  // B-frag read offsets (shorts): row (l31 + k), col i0; kbn 15 handled via c1off
  int off_r[KBN];
#pragma unroll
  for (int kbn = 0; kbn < 15; ++kbn) {
    int s = kbn * 16 + h * 8;
    int k = s / 48, i0 = s - 48 * k;
    off_r[kbn] = (l31 + k) * RS + i0;
  }
  off_r[15] = 0;   // unused; c1off passed separately

  const int n0w = wid * 32;
  const int ntH = wid & 1, mtH = wid >> 1;
  const int n0h = ntH * 32;
  const int c1w = (C1ROW - n0w) * RS;
  const int c1h = (C1ROW - n0h) * RS;

  int p = 0;

  {
    short8 Aw[2][KBN];
    load_wA32<2>(dw, db, Aw, 0, l31, h);
    zero_carry_c1(sb, tid);
    __syncthreads();
    // ---------------- DOWN: d[h] = x[h] + convW(d[h-1]) ----------------
    initW(sb, xbuf, (size_t)C_, du, n0w, l31, h4);
    run_passW(sb, p, Aw, off_r, c1w, H_ - 1,
              [&](int s) { return xbuf + (size_t)s * WC; }, (size_t)C_,
              [&](int s) { return du + (size_t)s * WC; }, n0w, l31, h4);
    __syncthreads();
    // ---------------- UP (down weights; carry = D[63] persists) --------
    run_passW(sb, p, Aw, off_r, c1w, H_ - 1,
              [&](int s) { int ih = (s <= H_ - 2) ? (H_ - 2 - s) : (H_ - 1);
                           return du + (size_t)ih * WC; }, (size_t)C_,
              [&](int s) { return du + (size_t)(H_ - 1 - s) * WC; }, n0w, l31, h4);
    __syncthreads();
  }

  // ---------------- RIGHT: r[t] = U[...,t] + convH(r[t-1]) -----------
  {
    short8 Ah[1][KBN];
    load_wA32<1>(rw, rb, Ah, mtH, l31, h);
    zero_carry_c1(sb, tid);
    __syncthreads();
    p = 0;
    if (mtH == 0) initH<0>(sb, du, (size_t)WC, rl, n0h, l31, h4);
    else          initH<1>(sb, du, (size_t)WC, rl, n0h, l31, h4);
    if (mtH == 0)
      run_passH<0>(sb, p, Ah[0], off_r, c1h, W_ - 1,
                   [&](int s) { return du + (size_t)s * C_; }, (size_t)WC,
                   [&](int s) { return rl + (size_t)s * HC; }, n0h, l31, h4);
    else
      run_passH<1>(sb, p, Ah[0], off_r, c1h, W_ - 1,
                   [&](int s) { return du + (size_t)s * C_; }, (size_t)WC,
                   [&](int s) { return rl + (size_t)s * HC; }, n0h, l31, h4);
    __syncthreads();
    // ---------------- LEFT (carry = R[127]; L[127]=R[127] in place) ----
    load_wA32<1>(lw, lb, Ah, mtH, l31, h);
    if (mtH == 0)
      run_passH<0>(sb, p, Ah[0], off_r, c1h, W_ - 1,
                   [&](int s) { return rl + (size_t)(W_ - 1 - s) * HC; }, (size_t)C_,
                   [&](int s) { return rl + (size_t)(W_ - 1 - s) * HC; }, n0h, l31, h4);
    else
      run_passH<1>(sb, p, Ah[0], off_r, c1h, W_ - 1,
                   [&](int s) { return rl + (size_t)(W_ - 1 - s) * HC; }, (size_t)C_,
                   [&](int s) { return rl + (size_t)(W_ - 1 - s) * HC; }, n0h, l31, h4);
  }
}

// x [b][c][h][w] -> xT [b][h][w][c]
__global__ __launch_bounds__(256) void xpose_chw_hwc(const float* __restrict__ x,
                                                     float* __restrict__ xT) {
  __shared__ float t[C_ * 129];
  const int bh = blockIdx.x, b = bh >> 6, hh = bh & 63;
  const float* src = x + (size_t)b * SLAB + (size_t)hh * W_;
  float* dst = xT + (size_t)b * SLAB + (size_t)hh * (W_ * C_);
  for (int i = threadIdx.x; i < C_ * W_; i += 256) {
    int c = i >> 7, w = i & 127;
    t[c * 129 + w] = src[(size_t)c * (H_ * W_) + w];
  }
  __syncthreads();
  for (int i = threadIdx.x; i < C_ * W_; i += 256) {
    int w = i / C_, c = i - w * C_;
    dst[i] = t[c * 129 + w];
  }
}

// L [b][w][h][c] -> out [b][c][h][w]
__global__ __launch_bounds__(256) void xpose_whc_chw(const float* __restrict__ L,
                                                     float* __restrict__ out) {
  __shared__ float t[W_ * 49];
  const int bh = blockIdx.x, b = bh >> 6, hh = bh & 63;
  const float* src = L + (size_t)b * SLAB + (size_t)hh * C_;
  float* dst = out + (size_t)b * SLAB + (size_t)hh * W_;
  for (int i = threadIdx.x; i < W_ * C_; i += 256) {
    int w = i / C_, c = i - w * C_;
    t[w * 49 + c] = src[(size_t)w * (H_ * C_) + c];
  }
  __syncthreads();
  for (int i = threadIdx.x; i < C_ * W_; i += 256) {
    int c = i >> 7, w = i & 127;
    dst[(size_t)c * (H_ * W_) + w] = t[w * 49 + c];
  }
}

extern "C" void kernel_launch(void* const* d_in, const int* in_sizes, int n_in,
                              void* d_out, int out_size, void* d_ws, size_t ws_size,
                              hipStream_t stream) {
  const float* x  = (const float*)d_in[0];
  const float* dw = (const float*)d_in[1];
  const float* db = (const float*)d_in[2];
  const float* rw = (const float*)d_in[3];
  const float* rb = (const float*)d_in[4];
  const float* lw = (const float*)d_in[5];
  const float* lb = (const float*)d_in[6];
  float* DU = (float*)d_out;
  float* WS = (float*)d_ws;

  xpose_chw_hwc<<<B_ * H_, 256, 0, stream>>>(x, WS);
  scnn_mfma<<<B_, 256, 0, stream>>>(WS, dw, db, rw, rb, lw, lb, DU);
  xpose_whc_chw<<<B_ * H_, 256, 0, stream>>>(WS, DU);
}

// Round 14
// 436.258 us; speedup vs baseline: 1.0013x; 1.0013x over previous
//
#include <hip/hip_runtime.h>
#include <hip/hip_bf16.h>

#define B_ 32
#define C_ 48
#define H_ 64
#define W_ 128
#define K_ 5
#define SLAB (C_*H_*W_)
#define RS 56                 // carry row stride in bf16 shorts (112 B)
#define ROWS 136              // rows 0..133 data+halo, row 135 = const-1 block
#define CBUF (ROWS*RS)
#define WC (W_*C_)
#define HC (H_*C_)
#define KBN 16                // K' = 256: 15 real kb (K'=240) + 1 bias/pad kb
#define C1ROW 135

typedef __attribute__((ext_vector_type(8))) short short8;
typedef __attribute__((ext_vector_type(16))) float f32x16;
typedef unsigned short ushort;

__device__ __forceinline__ void lbar() {
  asm volatile("s_waitcnt lgkmcnt(0)\n\ts_barrier" ::: "memory");
}

__device__ __forceinline__ unsigned short f2bf(float f) {
  union { float f; unsigned u; } v; v.f = f;
  unsigned r = v.u + 0x7fffu + ((v.u >> 16) & 1u);
  return (unsigned short)(r >> 16);
}

__device__ __forceinline__ unsigned pk2(float a, float b) {
  union { __hip_bfloat162 h; unsigned u; } z;
  z.h = __float22bfloat162_rn(float2{a, b});
  return z.u;
}

// Weights as 32x32x16 MFMA A operand. Lane l: m = mt*32 + (l&31),
// k' = kbn*16 + (l>>5)*8 + j. kp<240: dense k'=k*48+i; kp==240: bias[m]
// (pairs with const-1.0 B slot); else 0. m>=48 pad -> 0.
template<int NMT>
__device__ __forceinline__ void load_wA32(const float* __restrict__ wgt,
                                          const float* __restrict__ bias,
                                          short8 Aw[NMT][KBN], int mt0,
                                          int l31, int h) {
#pragma unroll
  for (int mti = 0; mti < NMT; ++mti) {
    const int m = (mt0 + mti) * 32 + l31;
#pragma unroll
    for (int kbn = 0; kbn < KBN; ++kbn) {
      short8 f;
#pragma unroll
      for (int j = 0; j < 8; ++j) {
        int kp = kbn * 16 + h * 8 + j;
        float val = 0.f;
        if (m < C_) {
          if (kp < 240) {
            int k = kp / 48, i = kp - 48 * k;
            val = wgt[m * (C_ * K_) + i * K_ + k];
          } else if (kp == 240) {
            val = bias[m];
          }
        }
        f[j] = (short)f2bf(val);
      }
      Aw[mti][kbn] = f;
    }
  }
}

// Load 6 channel-group float4s (W layout: mt0 g0-3, mt1 g0-1)
__device__ __forceinline__ void loadx6(float4 xv[6], const float* __restrict__ inp,
                                       size_t inRS, int n0, int l31, int h4) {
  const float* ip = inp + (size_t)(n0 + l31) * inRS + h4;
  xv[0] = *(const float4*)(ip + 0);
  xv[1] = *(const float4*)(ip + 8);
  xv[2] = *(const float4*)(ip + 16);
  xv[3] = *(const float4*)(ip + 24);
  xv[4] = *(const float4*)(ip + 32);
  xv[5] = *(const float4*)(ip + 40);
}

// ---- W step: 1 Ntile (32 rows) x 2 Mtiles, 32 MFMA.
// 4 accumulator chains a[mt][kbn&1] -> dependent-chain depth 8 (was 16).
__device__ __forceinline__ void stepW32(const ushort* __restrict__ scr,
                                        ushort* __restrict__ scw,
                                        const short8 Aw[2][KBN],
                                        const float4 xvc[6], float4 xvn[6],
                                        const float* __restrict__ inpn, size_t inRS,
                                        float* __restrict__ outp,
                                        int n0, int l31, int h4,
                                        const int off_r[KBN], int c1off) {
  f32x16 a00 = (f32x16)(0.0f), a01 = (f32x16)(0.0f);
  f32x16 a10 = (f32x16)(0.0f), a11 = (f32x16)(0.0f);
  const ushort* bp = scr + (size_t)n0 * RS;
#pragma unroll
  for (int kbn = 0; kbn < KBN; ++kbn) {
    int off = (kbn == 15) ? c1off : off_r[kbn];
    short8 pf = *(const short8*)(bp + off);
    if (kbn & 1) {
      a01 = __builtin_amdgcn_mfma_f32_32x32x16_bf16(Aw[0][kbn], pf, a01, 0, 0, 0);
      a11 = __builtin_amdgcn_mfma_f32_32x32x16_bf16(Aw[1][kbn], pf, a11, 0, 0, 0);
    } else {
      a00 = __builtin_amdgcn_mfma_f32_32x32x16_bf16(Aw[0][kbn], pf, a00, 0, 0, 0);
      a10 = __builtin_amdgcn_mfma_f32_32x32x16_bf16(Aw[1][kbn], pf, a10, 0, 0, 0);
    }
  }
  loadx6(xvn, inpn, inRS, n0, l31, h4);   // next-step inputs
  __builtin_amdgcn_sched_barrier(0);

  const int row = n0 + l31;
  float* op = outp + (size_t)row * C_ + h4;
  ushort* wp = scw + (size_t)(row + 2) * RS + h4;
#pragma unroll
  for (int grp = 0; grp < 6; ++grp) {
    const int g = (grp < 4) ? grp : (grp - 4);
    const int ch = ((grp < 4) ? 0 : 32) + 8 * g;
    float4 v;
    if (grp < 4) {
      v.x = a00[4*g+0] + a01[4*g+0] + xvc[grp].x;
      v.y = a00[4*g+1] + a01[4*g+1] + xvc[grp].y;
      v.z = a00[4*g+2] + a01[4*g+2] + xvc[grp].z;
      v.w = a00[4*g+3] + a01[4*g+3] + xvc[grp].w;
    } else {
      v.x = a10[4*g+0] + a11[4*g+0] + xvc[grp].x;
      v.y = a10[4*g+1] + a11[4*g+1] + xvc[grp].y;
      v.z = a10[4*g+2] + a11[4*g+2] + xvc[grp].z;
      v.w = a10[4*g+3] + a11[4*g+3] + xvc[grp].w;
    }
    *(float4*)(op + ch) = v;
    uint2 pk; pk.x = pk2(v.x, v.y); pk.y = pk2(v.z, v.w);
    *(uint2*)(wp + ch) = pk;
  }
  lbar();
}

// ---- H step: wave = (nt, mt); 16 MFMA, 4 accumulator chains (depth 4).
template<int MT>
__device__ __forceinline__ void stepH32(const ushort* __restrict__ scr,
                                        ushort* __restrict__ scw,
                                        const short8 Aw[KBN],
                                        const float4 xvc[4], float4 xvn[4],
                                        const float* __restrict__ inpn, size_t inRS,
                                        float* __restrict__ outp,
                                        int n0, int l31, int h4,
                                        const int off_r[KBN], int c1off) {
  constexpr int NG = MT ? 2 : 4;
  f32x16 a0 = (f32x16)(0.0f), a1 = (f32x16)(0.0f);
  f32x16 a2 = (f32x16)(0.0f), a3 = (f32x16)(0.0f);
  const ushort* bp = scr + (size_t)n0 * RS;
#pragma unroll
  for (int kbn = 0; kbn < KBN; ++kbn) {
    int off = (kbn == 15) ? c1off : off_r[kbn];
    short8 pf = *(const short8*)(bp + off);
    switch (kbn & 3) {
      case 0: a0 = __builtin_amdgcn_mfma_f32_32x32x16_bf16(Aw[kbn], pf, a0, 0, 0, 0); break;
      case 1: a1 = __builtin_amdgcn_mfma_f32_32x32x16_bf16(Aw[kbn], pf, a1, 0, 0, 0); break;
      case 2: a2 = __builtin_amdgcn_mfma_f32_32x32x16_bf16(Aw[kbn], pf, a2, 0, 0, 0); break;
      default: a3 = __builtin_amdgcn_mfma_f32_32x32x16_bf16(Aw[kbn], pf, a3, 0, 0, 0); break;
    }
  }
  const int row = n0 + l31;
  {
    const float* ip = inpn + (size_t)row * inRS + MT * 32 + h4;
#pragma unroll
    for (int g = 0; g < NG; ++g) xvn[g] = *(const float4*)(ip + 8 * g);
  }
  __builtin_amdgcn_sched_barrier(0);

  float* op = outp + (size_t)row * C_ + MT * 32 + h4;
  ushort* wp = scw + (size_t)(row + 2) * RS + MT * 32 + h4;
#pragma unroll
  for (int g = 0; g < NG; ++g) {
    float4 v;
    v.x = a0[4*g+0] + a1[4*g+0] + a2[4*g+0] + a3[4*g+0] + xvc[g].x;
    v.y = a0[4*g+1] + a1[4*g+1] + a2[4*g+1] + a3[4*g+1] + xvc[g].y;
    v.z = a0[4*g+2] + a1[4*g+2] + a2[4*g+2] + a3[4*g+2] + xvc[g].z;
    v.w = a0[4*g+3] + a1[4*g+3] + a2[4*g+3] + a3[4*g+3] + xvc[g].w;
    *(float4*)(op + 8 * g) = v;
    uint2 pk; pk.x = pk2(v.x, v.y); pk.y = pk2(v.z, v.w);
    *(uint2*)(wp + 8 * g) = pk;
  }
  lbar();
}

// Pass-initial: carry = inp, out = inp (W layout: 6 groups).
__device__ __forceinline__ void initW(ushort* __restrict__ scw,
                                      const float* __restrict__ inp, size_t inRS,
                                      float* __restrict__ outp,
                                      int n0, int l31, int h4) {
  const int row = n0 + l31;
  const float* ip = inp + (size_t)row * inRS + h4;
  float* op = outp + (size_t)row * C_ + h4;
  ushort* wp = scw + (size_t)(row + 2) * RS + h4;
#pragma unroll
  for (int grp = 0; grp < 6; ++grp) {
    const int g = (grp < 4) ? grp : (grp - 4);
    const int ch = ((grp < 4) ? 0 : 32) + 8 * g;
    float4 v = *(const float4*)(ip + ch);
    *(float4*)(op + ch) = v;
    uint2 pk; pk.x = pk2(v.x, v.y); pk.y = pk2(v.z, v.w);
    *(uint2*)(wp + ch) = pk;
  }
  lbar();
}

template<int MT>
__device__ __forceinline__ void initH(ushort* __restrict__ scw,
                                      const float* __restrict__ inp, size_t inRS,
                                      float* __restrict__ outp,
                                      int n0, int l31, int h4) {
  constexpr int NG = MT ? 2 : 4;
  const int row = n0 + l31;
  const float* ip = inp + (size_t)row * inRS + MT * 32 + h4;
  float* op = outp + (size_t)row * C_ + MT * 32 + h4;
  ushort* wp = scw + (size_t)(row + 2) * RS + MT * 32 + h4;
#pragma unroll
  for (int g = 0; g < NG; ++g) {
    float4 v = *(const float4*)(ip + 8 * g);
    *(float4*)(op + 8 * g) = v;
    uint2 pk; pk.x = pk2(v.x, v.y); pk.y = pk2(v.z, v.w);
    *(uint2*)(wp + 8 * g) = pk;
  }
  lbar();
}

template<class FIN, class FOUT>
__device__ __forceinline__ void run_passW(ushort* sb, int& p,
                                          const short8 Aw[2][KBN],
                                          const int off_r[KBN], int c1off,
                                          int nsteps, FIN inadr, size_t inRS, FOUT outadr,
                                          int n0, int l31, int h4) {
  float4 xa[6], xb[6];
  loadx6(xa, inadr(1), inRS, n0, l31, h4);
  for (int s = 1; s <= nsteps; s += 2) {
    {
      int sn = (s + 1 <= nsteps) ? s + 1 : nsteps;
      stepW32(sb + (size_t)p * CBUF, sb + (size_t)(p ^ 1) * CBUF, Aw, xa, xb,
              inadr(sn), inRS, outadr(s), n0, l31, h4, off_r, c1off);
      p ^= 1;
    }
    if (s + 1 <= nsteps) {
      int sn = (s + 2 <= nsteps) ? s + 2 : nsteps;
      stepW32(sb + (size_t)p * CBUF, sb + (size_t)(p ^ 1) * CBUF, Aw, xb, xa,
              inadr(sn), inRS, outadr(s + 1), n0, l31, h4, off_r, c1off);
      p ^= 1;
    }
  }
}

template<int MT, class FIN, class FOUT>
__device__ __forceinline__ void run_passH(ushort* sb, int& p,
                                          const short8 Aw[KBN],
                                          const int off_r[KBN], int c1off,
                                          int nsteps, FIN inadr, size_t inRS, FOUT outadr,
                                          int n0, int l31, int h4) {
  float4 xa[4], xb[4];
  {
    const float* ip = inadr(1) + (size_t)(n0 + l31) * inRS + MT * 32 + h4;
#pragma unroll
    for (int g = 0; g < (MT ? 2 : 4); ++g) xa[g] = *(const float4*)(ip + 8 * g);
  }
  for (int s = 1; s <= nsteps; s += 2) {
    {
      int sn = (s + 1 <= nsteps) ? s + 1 : nsteps;
      stepH32<MT>(sb + (size_t)p * CBUF, sb + (size_t)(p ^ 1) * CBUF, Aw, xa, xb,
                  inadr(sn), inRS, outadr(s), n0, l31, h4, off_r, c1off);
      p ^= 1;
    }
    if (s + 1 <= nsteps) {
      int sn = (s + 2 <= nsteps) ? s + 2 : nsteps;
      stepH32<MT>(sb + (size_t)p * CBUF, sb + (size_t)(p ^ 1) * CBUF, Aw, xb, xa,
                  inadr(sn), inRS, outadr(s + 1), n0, l31, h4, off_r, c1off);
      p ^= 1;
    }
  }
}

__device__ __forceinline__ void zero_carry_c1(ushort* sb, int tid) {
  unsigned* z = (unsigned*)sb;
  for (int i = tid; i < CBUF; i += 256) z[i] = 0u;   // zeroes both buffers
  __syncthreads();
  if (tid == 0) { sb[C1ROW * RS] = 0x3F80; sb[CBUF + C1ROW * RS] = 0x3F80; }
}

// 4 waves (256 thr) per batch, grid 32. 32x32x16 MFMA.
// W passes: wave = Ntile wid (32 rows) x full M. H: wave = (nt=wid&1, mt=wid>>1).
__global__ __launch_bounds__(256, 1) void scnn_mfma(
    float* ws,                       // xT [b][h][w][c]; then R/L [b][t][h][c] (alias)
    const float* __restrict__ dw, const float* __restrict__ db,
    const float* __restrict__ rw, const float* __restrict__ rb,
    const float* __restrict__ lw, const float* __restrict__ lb,
    float* __restrict__ DU)          // d_out: D/U slabs [b][h][w][c]
{
  __shared__ __align__(32) ushort sb[2 * CBUF];
  const int tid = threadIdx.x, lane = tid & 63, wid = tid >> 6;
  const int l31 = lane & 31, h = lane >> 5, h4 = h * 4;
  const int b = blockIdx.x;
  float* xbuf = ws + (size_t)b * SLAB;
  float* rl   = ws + (size_t)b * SLAB;
  float* du   = DU + (size_t)b * SLAB;

  // B-frag read offsets (shorts): row (l31 + k), col i0; kbn 15 handled via c1off
  int off_r[KBN];
#pragma unroll
  for (int kbn = 0; kbn < 15; ++kbn) {
    int s = kbn * 16 + h * 8;
    int k = s / 48, i0 = s - 48 * k;
    off_r[kbn] = (l31 + k) * RS + i0;
  }
  off_r[15] = 0;   // unused; c1off passed separately

  const int n0w = wid * 32;
  const int ntH = wid & 1, mtH = wid >> 1;
  const int n0h = ntH * 32;
  const int c1w = (C1ROW - n0w) * RS;
  const int c1h = (C1ROW - n0h) * RS;

  int p = 0;

  {
    short8 Aw[2][KBN];
    load_wA32<2>(dw, db, Aw, 0, l31, h);
    zero_carry_c1(sb, tid);
    __syncthreads();
    // ---------------- DOWN: d[h] = x[h] + convW(d[h-1]) ----------------
    initW(sb, xbuf, (size_t)C_, du, n0w, l31, h4);
    run_passW(sb, p, Aw, off_r, c1w, H_ - 1,
              [&](int s) { return xbuf + (size_t)s * WC; }, (size_t)C_,
              [&](int s) { return du + (size_t)s * WC; }, n0w, l31, h4);
    __syncthreads();
    // ---------------- UP (down weights; carry = D[63] persists) --------
    run_passW(sb, p, Aw, off_r, c1w, H_ - 1,
              [&](int s) { int ih = (s <= H_ - 2) ? (H_ - 2 - s) : (H_ - 1);
                           return du + (size_t)ih * WC; }, (size_t)C_,
              [&](int s) { return du + (size_t)(H_ - 1 - s) * WC; }, n0w, l31, h4);
    __syncthreads();
  }

  // ---------------- RIGHT: r[t] = U[...,t] + convH(r[t-1]) -----------
  {
    short8 Ah[1][KBN];
    load_wA32<1>(rw, rb, Ah, mtH, l31, h);
    zero_carry_c1(sb, tid);
    __syncthreads();
    p = 0;
    if (mtH == 0) initH<0>(sb, du, (size_t)WC, rl, n0h, l31, h4);
    else          initH<1>(sb, du, (size_t)WC, rl, n0h, l31, h4);
    if (mtH == 0)
      run_passH<0>(sb, p, Ah[0], off_r, c1h, W_ - 1,
                   [&](int s) { return du + (size_t)s * C_; }, (size_t)WC,
                   [&](int s) { return rl + (size_t)s * HC; }, n0h, l31, h4);
    else
      run_passH<1>(sb, p, Ah[0], off_r, c1h, W_ - 1,
                   [&](int s) { return du + (size_t)s * C_; }, (size_t)WC,
                   [&](int s) { return rl + (size_t)s * HC; }, n0h, l31, h4);
    __syncthreads();
    // ---------------- LEFT (carry = R[127]; L[127]=R[127] in place) ----
    load_wA32<1>(lw, lb, Ah, mtH, l31, h);
    if (mtH == 0)
      run_passH<0>(sb, p, Ah[0], off_r, c1h, W_ - 1,
                   [&](int s) { return rl + (size_t)(W_ - 1 - s) * HC; }, (size_t)C_,
                   [&](int s) { return rl + (size_t)(W_ - 1 - s) * HC; }, n0h, l31, h4);
    else
      run_passH<1>(sb, p, Ah[0], off_r, c1h, W_ - 1,
                   [&](int s) { return rl + (size_t)(W_ - 1 - s) * HC; }, (size_t)C_,
                   [&](int s) { return rl + (size_t)(W_ - 1 - s) * HC; }, n0h, l31, h4);
  }
}

// x [b][c][h][w] -> xT [b][h][w][c]
__global__ __launch_bounds__(256) void xpose_chw_hwc(const float* __restrict__ x,
                                                     float* __restrict__ xT) {
  __shared__ float t[C_ * 129];
  const int bh = blockIdx.x, b = bh >> 6, hh = bh & 63;
  const float* src = x + (size_t)b * SLAB + (size_t)hh * W_;
  float* dst = xT + (size_t)b * SLAB + (size_t)hh * (W_ * C_);
  for (int i = threadIdx.x; i < C_ * W_; i += 256) {
    int c = i >> 7, w = i & 127;
    t[c * 129 + w] = src[(size_t)c * (H_ * W_) + w];
  }
  __syncthreads();
  for (int i = threadIdx.x; i < C_ * W_; i += 256) {
    int w = i / C_, c = i - w * C_;
    dst[i] = t[c * 129 + w];
  }
}

// L [b][w][h][c] -> out [b][c][h][w]
__global__ __launch_bounds__(256) void xpose_whc_chw(const float* __restrict__ L,
                                                     float* __restrict__ out) {
  __shared__ float t[W_ * 49];
  const int bh = blockIdx.x, b = bh >> 6, hh = bh & 63;
  const float* src = L + (size_t)b * SLAB + (size_t)hh * C_;
  float* dst = out + (size_t)b * SLAB + (size_t)hh * W_;
  for (int i = threadIdx.x; i < W_ * C_; i += 256) {
    int w = i / C_, c = i - w * C_;
    t[w * 49 + c] = src[(size_t)w * (H_ * C_) + c];
  }
  __syncthreads();
  for (int i = threadIdx.x; i < C_ * W_; i += 256) {
    int c = i >> 7, w = i & 127;
    dst[(size_t)c * (H_ * W_) + w] = t[w * 49 + c];
  }
}

extern "C" void kernel_launch(void* const* d_in, const int* in_sizes, int n_in,
                              void* d_out, int out_size, void* d_ws, size_t ws_size,
                              hipStream_t stream) {
  const float* x  = (const float*)d_in[0];
  const float* dw = (const float*)d_in[1];
  const float* db = (const float*)d_in[2];
  const float* rw = (const float*)d_in[3];
  const float* rb = (const float*)d_in[4];
  const float* lw = (const float*)d_in[5];
  const float* lb = (const float*)d_in[6];
  float* DU = (float*)d_out;
  float* WS = (float*)d_ws;

  xpose_chw_hwc<<<B_ * H_, 256, 0, stream>>>(x, WS);
  scnn_mfma<<<B_, 256, 0, stream>>>(WS, dw, db, rw, rb, lw, lb, DU);
  xpose_whc_chw<<<B_ * H_, 256, 0, stream>>>(WS, DU);
}

// Round 15
// 428.993 us; speedup vs baseline: 1.0183x; 1.0169x over previous
//
#include <hip/hip_runtime.h>
#include <hip/hip_bf16.h>

#define B_ 32
#define C_ 48
#define H_ 64
#define W_ 128
#define K_ 5
#define SLAB (C_*H_*W_)
#define RS 56                 // carry row stride in bf16 shorts (112 B)
#define ROWS 136              // rows 0..133 data+halo, row 135 = const-1 block
#define CBUF (ROWS*RS)
#define WC (W_*C_)
#define HC (H_*C_)
#define KB32 16               // W passes: 32x32x16, K'=256 (240 dense + bias kb)
#define KB16 8                // H passes: 16x16x32, K'=256 dense (240 + pad)
#define C1ROW 135

typedef __attribute__((ext_vector_type(8))) short short8;
typedef __attribute__((ext_vector_type(4))) float f32x4;
typedef __attribute__((ext_vector_type(16))) float f32x16;
typedef unsigned short ushort;

__device__ __forceinline__ void lbar() {
  asm volatile("s_waitcnt lgkmcnt(0)\n\ts_barrier" ::: "memory");
}

__device__ __forceinline__ unsigned short f2bf(float f) {
  union { float f; unsigned u; } v; v.f = f;
  unsigned r = v.u + 0x7fffu + ((v.u >> 16) & 1u);
  return (unsigned short)(r >> 16);
}

__device__ __forceinline__ unsigned pk2(float a, float b) {
  union { __hip_bfloat162 h; unsigned u; } z;
  z.h = __float22bfloat162_rn(float2{a, b});
  return z.u;
}

// ================= W-pass side (32x32x16, from R13/R14) =================
// A[m][k']: m = mt*32 + (l&31); k' = kbn*16 + (l>>5)*8 + j.
// kp<240: dense k'=k*48+i; kp==240: bias[m] (pairs with const-1 B slot).
__device__ __forceinline__ void load_wA32(const float* __restrict__ wgt,
                                          const float* __restrict__ bias,
                                          short8 Aw[2][KB32], int l31, int hh) {
#pragma unroll
  for (int mti = 0; mti < 2; ++mti) {
    const int m = mti * 32 + l31;
#pragma unroll
    for (int kbn = 0; kbn < KB32; ++kbn) {
      short8 f;
#pragma unroll
      for (int j = 0; j < 8; ++j) {
        int kp = kbn * 16 + hh * 8 + j;
        float val = 0.f;
        if (m < C_) {
          if (kp < 240) {
            int k = kp / 48, i = kp - 48 * k;
            val = wgt[m * (C_ * K_) + i * K_ + k];
          } else if (kp == 240) {
            val = bias[m];
          }
        }
        f[j] = (short)f2bf(val);
      }
      Aw[mti][kbn] = f;
    }
  }
}

__device__ __forceinline__ void loadx6(float4 xv[6], const float* __restrict__ inp,
                                       size_t inRS, int n0, int l31, int h4) {
  const float* ip = inp + (size_t)(n0 + l31) * inRS + h4;
  xv[0] = *(const float4*)(ip + 0);
  xv[1] = *(const float4*)(ip + 8);
  xv[2] = *(const float4*)(ip + 16);
  xv[3] = *(const float4*)(ip + 24);
  xv[4] = *(const float4*)(ip + 32);
  xv[5] = *(const float4*)(ip + 40);
}

__device__ __forceinline__ void stepW32(const ushort* __restrict__ scr,
                                        ushort* __restrict__ scw,
                                        const short8 Aw[2][KB32],
                                        const float4 xvc[6], float4 xvn[6],
                                        const float* __restrict__ inpn, size_t inRS,
                                        float* __restrict__ outp,
                                        int n0, int l31, int h4,
                                        const int off32[KB32], int c1off) {
  f32x16 a00 = (f32x16)(0.0f), a01 = (f32x16)(0.0f);
  f32x16 a10 = (f32x16)(0.0f), a11 = (f32x16)(0.0f);
  const ushort* bp = scr + (size_t)n0 * RS;
#pragma unroll
  for (int kbn = 0; kbn < KB32; ++kbn) {
    int off = (kbn == 15) ? c1off : off32[kbn];
    short8 pf = *(const short8*)(bp + off);
    if (kbn & 1) {
      a01 = __builtin_amdgcn_mfma_f32_32x32x16_bf16(Aw[0][kbn], pf, a01, 0, 0, 0);
      a11 = __builtin_amdgcn_mfma_f32_32x32x16_bf16(Aw[1][kbn], pf, a11, 0, 0, 0);
    } else {
      a00 = __builtin_amdgcn_mfma_f32_32x32x16_bf16(Aw[0][kbn], pf, a00, 0, 0, 0);
      a10 = __builtin_amdgcn_mfma_f32_32x32x16_bf16(Aw[1][kbn], pf, a10, 0, 0, 0);
    }
  }
  loadx6(xvn, inpn, inRS, n0, l31, h4);   // next-step inputs
  __builtin_amdgcn_sched_barrier(0);

  const int row = n0 + l31;
  float* op = outp + (size_t)row * C_ + h4;
  ushort* wp = scw + (size_t)(row + 2) * RS + h4;
#pragma unroll
  for (int grp = 0; grp < 6; ++grp) {
    const int g = (grp < 4) ? grp : (grp - 4);
    const int ch = ((grp < 4) ? 0 : 32) + 8 * g;
    float4 v;
    if (grp < 4) {
      v.x = a00[4*g+0] + a01[4*g+0] + xvc[grp].x;
      v.y = a00[4*g+1] + a01[4*g+1] + xvc[grp].y;
      v.z = a00[4*g+2] + a01[4*g+2] + xvc[grp].z;
      v.w = a00[4*g+3] + a01[4*g+3] + xvc[grp].w;
    } else {
      v.x = a10[4*g+0] + a11[4*g+0] + xvc[grp].x;
      v.y = a10[4*g+1] + a11[4*g+1] + xvc[grp].y;
      v.z = a10[4*g+2] + a11[4*g+2] + xvc[grp].z;
      v.w = a10[4*g+3] + a11[4*g+3] + xvc[grp].w;
    }
    *(float4*)(op + ch) = v;
    uint2 pk; pk.x = pk2(v.x, v.y); pk.y = pk2(v.z, v.w);
    *(uint2*)(wp + ch) = pk;
  }
  lbar();
}

__device__ __forceinline__ void initW(ushort* __restrict__ scw,
                                      const float* __restrict__ inp, size_t inRS,
                                      float* __restrict__ outp,
                                      int n0, int l31, int h4) {
  const int row = n0 + l31;
  const float* ip = inp + (size_t)row * inRS + h4;
  float* op = outp + (size_t)row * C_ + h4;
  ushort* wp = scw + (size_t)(row + 2) * RS + h4;
#pragma unroll
  for (int grp = 0; grp < 6; ++grp) {
    const int g = (grp < 4) ? grp : (grp - 4);
    const int ch = ((grp < 4) ? 0 : 32) + 8 * g;
    float4 v = *(const float4*)(ip + ch);
    *(float4*)(op + ch) = v;
    uint2 pk; pk.x = pk2(v.x, v.y); pk.y = pk2(v.z, v.w);
    *(uint2*)(wp + ch) = pk;
  }
  lbar();
}

template<class FIN, class FOUT>
__device__ __forceinline__ void run_passW(ushort* sb, int& p,
                                          const short8 Aw[2][KB32],
                                          const int off32[KB32], int c1off,
                                          int nsteps, FIN inadr, size_t inRS, FOUT outadr,
                                          int n0, int l31, int h4) {
  float4 xa[6], xb[6];
  loadx6(xa, inadr(1), inRS, n0, l31, h4);
  for (int s = 1; s <= nsteps; s += 2) {
    {
      int sn = (s + 1 <= nsteps) ? s + 1 : nsteps;
      stepW32(sb + (size_t)p * CBUF, sb + (size_t)(p ^ 1) * CBUF, Aw, xa, xb,
              inadr(sn), inRS, outadr(s), n0, l31, h4, off32, c1off);
      p ^= 1;
    }
    if (s + 1 <= nsteps) {
      int sn = (s + 2 <= nsteps) ? s + 2 : nsteps;
      stepW32(sb + (size_t)p * CBUF, sb + (size_t)(p ^ 1) * CBUF, Aw, xb, xa,
              inadr(sn), inRS, outadr(s + 1), n0, l31, h4, off32, c1off);
      p ^= 1;
    }
  }
}

// ================= H-pass side (16x16x32, from R7) =================
// A[m][k']: m = mt*16 + (l&15); k' = kb*32 + (l>>4)*8 + j; dense k'=k*48+i,
// pad >=240 -> 0. Bias in bv registers.
__device__ __forceinline__ void load_wA16(const float* __restrict__ wgt,
                                          const float* __restrict__ bias,
                                          short8 Ah[3][KB16], f32x4 bv[3],
                                          int l15, int q8, int c0) {
#pragma unroll
  for (int mt = 0; mt < 3; ++mt) {
#pragma unroll
    for (int r = 0; r < 4; ++r) bv[mt][r] = bias[mt * 16 + c0 + r];
#pragma unroll
    for (int kb = 0; kb < KB16; ++kb) {
      short8 f;
#pragma unroll
      for (int j = 0; j < 8; ++j) {
        int kp = kb * 32 + q8 + j;
        int k = kp / 48, i = kp - 48 * k;
        f[j] = (kp < 240)
             ? (short)f2bf(wgt[(mt * 16 + l15) * (C_ * K_) + i * K_ + k])
             : (short)0;
      }
      Ah[mt][kb] = f;
    }
  }
}

__device__ __forceinline__ void load_xin1(float4 xv[3], const float* __restrict__ inp,
                                          size_t lRS, int n0, int l15, int c0) {
  const float* p = inp + (size_t)(n0 + l15) * lRS + c0;
#pragma unroll
  for (int mt = 0; mt < 3; ++mt) xv[mt] = *(const float4*)(p + mt * 16);
}

__device__ __forceinline__ void stepH16(const ushort* __restrict__ scr,
                                        ushort* __restrict__ scw,
                                        const short8 Ah[3][KB16], const f32x4 bv[3],
                                        const float4 xv[3], const int off16[KB16],
                                        float* __restrict__ outp,
                                        int n0, int l15, int c0) {
  f32x4 acc[4][3];
#pragma unroll
  for (int s = 0; s < 4; ++s)
#pragma unroll
    for (int mt = 0; mt < 3; ++mt)
      acc[s][mt] = (s == 0) ? bv[mt] : (f32x4){0.f, 0.f, 0.f, 0.f};

#pragma unroll
  for (int kb = 0; kb < KB16; ++kb) {
    short8 pf = *(const short8*)(scr + (size_t)n0 * RS + off16[kb]);
#pragma unroll
    for (int mt = 0; mt < 3; ++mt)
      acc[kb % 4][mt] = __builtin_amdgcn_mfma_f32_16x16x32_bf16(
          Ah[mt][kb], pf, acc[kb % 4][mt], 0, 0, 0);
  }

  const int row = n0 + l15;
#pragma unroll
  for (int mt = 0; mt < 3; ++mt) {
    float4 v;
    v.x = acc[0][mt][0] + acc[1][mt][0] + acc[2][mt][0] + acc[3][mt][0] + xv[mt].x;
    v.y = acc[0][mt][1] + acc[1][mt][1] + acc[2][mt][1] + acc[3][mt][1] + xv[mt].y;
    v.z = acc[0][mt][2] + acc[1][mt][2] + acc[2][mt][2] + acc[3][mt][2] + xv[mt].z;
    v.w = acc[0][mt][3] + acc[1][mt][3] + acc[2][mt][3] + acc[3][mt][3] + xv[mt].w;
    *(float4*)(outp + (size_t)row * C_ + mt * 16 + c0) = v;
    uint2 pk; pk.x = pk2(v.x, v.y); pk.y = pk2(v.z, v.w);
    *(uint2*)(scw + (size_t)(row + 2) * RS + mt * 16 + c0) = pk;
  }
  lbar();
}

__device__ __forceinline__ void initH16(ushort* __restrict__ scw,
                                        const float* __restrict__ inp, size_t lRS,
                                        float* __restrict__ outp,
                                        int n0, int l15, int c0) {
  const int row = n0 + l15;
  const float* p = inp + (size_t)row * lRS + c0;
#pragma unroll
  for (int mt = 0; mt < 3; ++mt) {
    float4 v = *(const float4*)(p + mt * 16);
    *(float4*)(outp + (size_t)row * C_ + mt * 16 + c0) = v;
    uint2 pk; pk.x = pk2(v.x, v.y); pk.y = pk2(v.z, v.w);
    *(uint2*)(scw + (size_t)(row + 2) * RS + mt * 16 + c0) = pk;
  }
  lbar();
}

template<class FIN, class FOUT>
__device__ __forceinline__ void run_passH(ushort* sb, int& p,
                                          const short8 Ah[3][KB16], const f32x4 bv[3],
                                          const int off16[KB16],
                                          int nsteps, FIN inadr, size_t lRS, FOUT outadr,
                                          int n0, int l15, int c0) {
  float4 xa[3], xb[3];
  load_xin1(xa, inadr(1), lRS, n0, l15, c0);
  for (int s = 1; s <= nsteps; s += 2) {
    {
      int sn = (s + 1 <= nsteps) ? s + 1 : nsteps;
      load_xin1(xb, inadr(sn), lRS, n0, l15, c0);
      __builtin_amdgcn_sched_barrier(0x38F);
      stepH16(sb + (size_t)p * CBUF, sb + (size_t)(p ^ 1) * CBUF,
              Ah, bv, xa, off16, outadr(s), n0, l15, c0);
      p ^= 1;
    }
    if (s + 1 <= nsteps) {
      int sn = (s + 2 <= nsteps) ? s + 2 : nsteps;
      load_xin1(xa, inadr(sn), lRS, n0, l15, c0);
      __builtin_amdgcn_sched_barrier(0x38F);
      stepH16(sb + (size_t)p * CBUF, sb + (size_t)(p ^ 1) * CBUF,
              Ah, bv, xb, off16, outadr(s + 1), n0, l15, c0);
      p ^= 1;
    }
  }
}

// 4 waves (256 thr) per batch, grid 32.
// W passes: 32x32x16, wave = 32-row Ntile x full M (bias via const-1 slot).
// H passes: 16x16x32, wave = 16-row Ntile x full M (R7 structure).
__global__ __launch_bounds__(256, 1) void scnn_mfma(
    float* ws,                       // xT [b][h][w][c]; then R/L [b][t][h][c] (alias)
    const float* __restrict__ dw, const float* __restrict__ db,
    const float* __restrict__ rw, const float* __restrict__ rb,
    const float* __restrict__ lw, const float* __restrict__ lb,
    float* __restrict__ DU)          // d_out: D/U slabs [b][h][w][c]
{
  __shared__ __align__(32) ushort sb[2 * CBUF];
  const int tid = threadIdx.x, lane = tid & 63, wid = tid >> 6;
  const int l31 = lane & 31, hh = lane >> 5, h4 = hh * 4;
  const int l15 = lane & 15, q = lane >> 4, q8 = q * 8, c0 = 4 * q;
  const int b = blockIdx.x;
  float* xbuf = ws + (size_t)b * SLAB;
  float* rl   = ws + (size_t)b * SLAB;
  float* du   = DU + (size_t)b * SLAB;

  // W offsets (shorts): row (l31 + k), col i0
  int off32[KB32];
#pragma unroll
  for (int kbn = 0; kbn < 15; ++kbn) {
    int s = kbn * 16 + hh * 8;
    int k = s / 48, i0 = s - 48 * k;
    off32[kbn] = (l31 + k) * RS + i0;
  }
  off32[15] = 0;
  // H offsets (shorts): row (l15 + k), col i0
  int off16[KB16];
#pragma unroll
  for (int kb = 0; kb < KB16; ++kb) {
    int s = kb * 32 + q8;
    int k = s / 48, i0 = s - 48 * k;
    off16[kb] = (l15 + k) * RS + i0;
  }

  const int n0w = wid * 32, n0h = wid * 16;
  const int c1w = (C1ROW - n0w) * RS;
  int p = 0;

  // ================= W passes (DOWN, UP) =================
  {
    short8 Aw[2][KB32];
    load_wA32(dw, db, Aw, l31, hh);
    { unsigned* z = (unsigned*)sb; for (int i = tid; i < CBUF; i += 256) z[i] = 0u; }
    __syncthreads();
    if (tid == 0) { sb[C1ROW * RS] = 0x3F80; sb[CBUF + C1ROW * RS] = 0x3F80; }
    __syncthreads();
    initW(sb, xbuf, (size_t)C_, du, n0w, l31, h4);
    run_passW(sb, p, Aw, off32, c1w, H_ - 1,
              [&](int s) { return xbuf + (size_t)s * WC; }, (size_t)C_,
              [&](int s) { return du + (size_t)s * WC; }, n0w, l31, h4);
    __syncthreads();
    run_passW(sb, p, Aw, off32, c1w, H_ - 1,
              [&](int s) { int ih = (s <= H_ - 2) ? (H_ - 2 - s) : (H_ - 1);
                           return du + (size_t)ih * WC; }, (size_t)C_,
              [&](int s) { return du + (size_t)(H_ - 1 - s) * WC; }, n0w, l31, h4);
    __syncthreads();
  }

  // ================= H passes (RIGHT, LEFT) =================
  {
    short8 Ah[3][KB16];
    f32x4 bv[3];
    load_wA16(rw, rb, Ah, bv, l15, q8, c0);
    { unsigned* z = (unsigned*)sb; for (int i = tid; i < CBUF; i += 256) z[i] = 0u; }
    __syncthreads();
    p = 0;
    initH16(sb, du, (size_t)WC, rl, n0h, l15, c0);
    run_passH(sb, p, Ah, bv, off16, W_ - 1,
              [&](int s) { return du + (size_t)s * C_; }, (size_t)WC,
              [&](int s) { return rl + (size_t)s * HC; }, n0h, l15, c0);
    __syncthreads();
    load_wA16(lw, lb, Ah, bv, l15, q8, c0);
    run_passH(sb, p, Ah, bv, off16, W_ - 1,
              [&](int s) { return rl + (size_t)(W_ - 1 - s) * HC; }, (size_t)C_,
              [&](int s) { return rl + (size_t)(W_ - 1 - s) * HC; }, n0h, l15, c0);
  }
}

// x [b][c][h][w] -> xT [b][h][w][c]
__global__ __launch_bounds__(256) void xpose_chw_hwc(const float* __restrict__ x,
                                                     float* __restrict__ xT) {
  __shared__ float t[C_ * 129];
  const int bh = blockIdx.x, b = bh >> 6, hrow = bh & 63;
  const float* src = x + (size_t)b * SLAB + (size_t)hrow * W_;
  float* dst = xT + (size_t)b * SLAB + (size_t)hrow * (W_ * C_);
  for (int i = threadIdx.x; i < C_ * W_; i += 256) {
    int c = i >> 7, w = i & 127;
    t[c * 129 + w] = src[(size_t)c * (H_ * W_) + w];
  }
  __syncthreads();
  for (int i = threadIdx.x; i < C_ * W_; i += 256) {
    int w = i / C_, c = i - w * C_;
    dst[i] = t[c * 129 + w];
  }
}

// L [b][w][h][c] -> out [b][c][h][w]
__global__ __launch_bounds__(256) void xpose_whc_chw(const float* __restrict__ L,
                                                     float* __restrict__ out) {
  __shared__ float t[W_ * 49];
  const int bh = blockIdx.x, b = bh >> 6, hrow = bh & 63;
  const float* src = L + (size_t)b * SLAB + (size_t)hrow * C_;
  float* dst = out + (size_t)b * SLAB + (size_t)hrow * W_;
  for (int i = threadIdx.x; i < W_ * C_; i += 256) {
    int w = i / C_, c = i - w * C_;
    t[w * 49 + c] = src[(size_t)w * (H_ * C_) + c];
  }
  __syncthreads();
  for (int i = threadIdx.x; i < C_ * W_; i += 256) {
    int c = i >> 7, w = i & 127;
    dst[(size_t)c * (H_ * W_) + w] = t[w * 49 + c];
  }
}

extern "C" void kernel_launch(void* const* d_in, const int* in_sizes, int n_in,
                              void* d_out, int out_size, void* d_ws, size_t ws_size,
                              hipStream_t stream) {
  const float* x  = (const float*)d_in[0];
  const float* dw = (const float*)d_in[1];
  const float* db = (const float*)d_in[2];
  const float* rw = (const float*)d_in[3];
  const float* rb = (const float*)d_in[4];
  const float* lw = (const float*)d_in[5];
  const float* lb = (const float*)d_in[6];
  float* DU = (float*)d_out;
  float* WS = (float*)d_ws;

  xpose_chw_hwc<<<B_ * H_, 256, 0, stream>>>(x, WS);
  scnn_mfma<<<B_, 256, 0, stream>>>(WS, dw, db, rw, rb, lw, lb, DU);
  xpose_whc_chw<<<B_ * H_, 256, 0, stream>>>(WS, DU);
}